// Round 5
// baseline (336.920 us; speedup 1.0000x reference)
//
#include <hip/hip_runtime.h>

#define HW 512
#define RA 0.35355339059327373f
#define RB 0.25f

__device__ __forceinline__ int reflect512(int v) {
    v = v < 0 ? -v : v;
    v = v > 511 ? 1022 - v : v;
    return v;
}

__device__ __forceinline__ float softt2(float x) {
    // soft-threshold at lambda=0.1 (operates on 2x-scaled Haar values)
    return copysignf(fmaxf(fabsf(x) - 0.1f, 0.0f), x);
}

__device__ __forceinline__ float nlin(float t) {
    float ca = fabsf(t);
    t = (ca < 2.5f) ? t * (ca * 0.4f) : t;
    return fminf(fmaxf(t, -10.0f), 10.0f);
}

// Haar refine, the two 0.5 scales folded into one 0.25 (exact: pow2 scaling
// commutes with rounding; 0.05f == 0.5f*0.1f exactly).
__device__ __forceinline__ void haar_quad(float a, float b, float c, float d,
                                          float& oa, float& ob, float& oc, float& od) {
    float s1 = a + b, s2 = c + d, d1 = a - b, d2 = c - d;
    float LL = s1 + s2, LH = s1 - s2, HL = d1 + d2, HH = d1 - d2;  // 2x scaled
    LH = softt2(LH); HL = softt2(HL); HH = softt2(HH);
    float u1 = LL + LH, u2 = HL + HH, w1 = LL - LH, w2 = HL - HH;
    oa = (u1 + u2) * 0.25f; ob = (u1 - u2) * 0.25f;
    oc = (w1 + w2) * 0.25f; od = (w1 - w2) * 0.25f;
}

// 8-pt cos-DFT, distinct outputs only (full: [t0,t1,t2,t3,t4,t3,t2,t1])
__device__ __forceinline__ void cos5(const float* __restrict__ x, float* __restrict__ t) {
    float e0 = x[0] + x[4], d0 = x[0] - x[4];
    float e1 = x[2] + x[6];
    float o0 = x[1] + x[5], m0 = x[1] - x[5];
    float o1 = x[3] + x[7], m1 = x[3] - x[7];
    float see = e0 + e1, dee = e0 - e1, soo = o0 + o1, dd = m0 - m1;
    t[0] = RA * (see + soo);
    t[4] = RA * (see - soo);
    t[2] = RA * dee;
    float a = RA * d0, b = RB * dd;
    t[1] = a + b;
    t[3] = a - b;
}

// 8-pt sin-DFT, distinct outputs only (full: [0,s0,s1,s2,0,-s2,-s1,-s0])
__device__ __forceinline__ void sin3(const float* __restrict__ x, float* __restrict__ s) {
    float d1 = x[2] - x[6];
    float m0 = x[1] - x[5];
    float o0 = x[1] + x[5];
    float o1 = x[3] + x[7], m1 = x[3] - x[7];
    float qq = m0 + m1;
    float a = RB * qq, b = RA * d1;
    s[0] = a + b;
    s[1] = RA * (o0 - o1);
    s[2] = a - b;
}

// cos-DFT of a symmetric 8-vector [x0,x1,x2,x3,x4,x3,x2,x1] (exact specialization)
__device__ __forceinline__ void cos5_sym(const float* __restrict__ x, float* __restrict__ t) {
    float e0 = x[0] + x[4], d0 = x[0] - x[4];
    float tx2 = 2.0f * x[2];
    float see = e0 + tx2, dee = e0 - tx2;
    float soo = 2.0f * (x[1] + x[3]);
    float m0 = x[1] - x[3];
    t[0] = RA * (see + soo);
    t[4] = RA * (see - soo);
    t[2] = RA * dee;
    float a = RA * d0, b = 0.5f * m0;   // RB * (2*m0)
    t[1] = a + b;
    t[3] = a - b;
}

// sin-DFT of an antisymmetric 8-vector [0,y0,y1,y2,0,-y2,-y1,-y0] (exact specialization)
__device__ __forceinline__ void sin3_asym(const float* __restrict__ y, float* __restrict__ s) {
    float a = 0.5f * (y[0] + y[2]);          // RB * (2*(y0+y2))
    float b = (2.0f * RA) * y[1];            // RA * (2*y1)
    s[0] = a + b;
    s[1] = (2.0f * RA) * (y[0] - y[2]);
    s[2] = a - b;
}

// Inverse 2D transform from the 34-value symmetric form to the 34-value
// centro-symmetric spatial form. Identical algebra to the verified round-0/3 path.
__device__ __forceinline__ void inverse34(
    const float c0[5], const float c4[5], const float tt[3], const float bb[3],
    const float A[3][3], const float Bm[3][3],
    float Rc0[5], float Rc4[5], float r0v[3], float r4v[3],
    float RAm[3][3], float RBm[3][3]) {
    // ---- inverse row pass: rows 0,4 symmetric; rows 5..7 mirror 3..1 ----
    float p2[5][5], q2[3][3];
    {
        float x0[5] = {c0[0], tt[0], tt[1], tt[2], c4[0]};
        cos5_sym(x0, p2[0]);
        float x4[5] = {c0[4], bb[0], bb[1], bb[2], c4[4]};
        cos5_sym(x4, p2[4]);
    }
#pragma unroll
    for (int u = 1; u <= 3; ++u) {
        float r8[8] = {c0[u], A[0][u - 1], A[1][u - 1], A[2][u - 1], c4[u],
                       Bm[2][u - 1], Bm[1][u - 1], Bm[0][u - 1]};
        cos5(r8, p2[u]);
        sin3(r8, q2[u - 1]);
    }
    // ---- inverse column pass: p2 cols symmetric, q2 cols antisymmetric ----
    {
        float cc0[5] = {p2[0][0], p2[1][0], p2[2][0], p2[3][0], p2[4][0]};
        cos5_sym(cc0, Rc0);
        float cc4[5] = {p2[0][4], p2[1][4], p2[2][4], p2[3][4], p2[4][4]};
        cos5_sym(cc4, Rc4);
    }
#pragma unroll
    for (int vi = 0; vi < 3; ++vi) {
        int v = vi + 1;
        float cs[5] = {p2[0][v], p2[1][v], p2[2][v], p2[3][v], p2[4][v]};
        float t[5];
        cos5_sym(cs, t);
        float y[3] = {q2[0][vi], q2[1][vi], q2[2][vi]};
        float s[3];
        sin3_asym(y, s);
        r0v[vi] = t[0];
        r4v[vi] = t[4];
#pragma unroll
        for (int ui = 0; ui < 3; ++ui) {
            RAm[vi][ui] = t[ui + 1] - s[ui];
            RBm[vi][ui] = t[ui + 1] + s[ui];
        }
    }
}

// Expand centro-symmetric 34-form to 8x8 (pure renames, SSA-aliased by regalloc).
__device__ __forceinline__ void expand34(
    const float Rc0[5], const float Rc4[5], const float r0v[3], const float r4v[3],
    const float RAm[3][3], const float RBm[3][3], float rec[8][8]) {
#pragma unroll
    for (int u = 0; u < 8; ++u) {
        int us = (u <= 4) ? u : 8 - u;
        rec[u][0] = Rc0[us];
        rec[u][4] = Rc4[us];
    }
#pragma unroll
    for (int v = 1; v < 8; ++v) {
        if (v == 4) continue;
        int vs = (v <= 4) ? v : 8 - v;
        bool vf = v > 4;
        rec[0][v] = r0v[vs - 1];
        rec[4][v] = r4v[vs - 1];
#pragma unroll
        for (int u = 1; u < 8; ++u) {
            if (u == 4) continue;
            int us = (u <= 4) ? u : 8 - u;
            bool uf = u > 4;
            rec[u][v] = (vf != uf) ? RBm[vs - 1][us - 1] : RAm[vs - 1][us - 1];
        }
    }
}

__device__ __forceinline__ void haar_store(const float rec[8][8],
                                           float* __restrict__ o, int by, int cx) {
#pragma unroll
    for (int qy = 0; qy < 4; ++qy) {
        float ti[2][8];
#pragma unroll
        for (int qx = 0; qx < 4; ++qx) {
            haar_quad(rec[2 * qy][2 * qx], rec[2 * qy][2 * qx + 1],
                      rec[2 * qy + 1][2 * qx], rec[2 * qy + 1][2 * qx + 1],
                      ti[0][2 * qx], ti[0][2 * qx + 1], ti[1][2 * qx], ti[1][2 * qx + 1]);
        }
        size_t base = (size_t)(by * 8 + 2 * qy) * HW + cx;
        *(float4*)&o[base]          = make_float4(ti[0][0], ti[0][1], ti[0][2], ti[0][3]);
        *(float4*)&o[base + 4]      = make_float4(ti[0][4], ti[0][5], ti[0][6], ti[0][7]);
        *(float4*)&o[base + HW]     = make_float4(ti[1][0], ti[1][1], ti[1][2], ti[1][3]);
        *(float4*)&o[base + HW + 4] = make_float4(ti[1][4], ti[1][5], ti[1][6], ti[1][7]);
    }
}

__launch_bounds__(256, 4)
__global__ void sas_fused(const float* __restrict__ in, float* __restrict__ out) {
    const int lane = threadIdx.x & 63;   // block-col 0..63
    const int wv = threadIdx.x >> 6;     // wave in workgroup
    const int p = blockIdx.y;            // plane (b*3+c)
    const int by = blockIdx.x * 4 + wv;  // block-row 0..63
    const float* __restrict__ inP = in + (size_t)p * (HW * HW);
    const int cx = lane * 8;

    const float e = 0.45783336f;                  // exp(-1/1.28)
    const float inv_s = 1.0f / ((1.0f + 2.0f * e) * (1.0f + 2.0f * e));

    // ---- issue ALL 10 row-loads upfront; sched_barrier pins them above consumption ----
    float4 va[10], vb[10];
#pragma unroll
    for (int j = 0; j < 10; ++j) {
        int gy = reflect512(by * 8 - 1 + j);
        const float* r = inP + (size_t)gy * HW + cx;
        va[j] = *(const float4*)r;
        vb[j] = *(const float4*)(r + 4);
    }
    __builtin_amdgcn_sched_barrier(0);   // keep all 20 loads in flight (MLP)

    // ---- streamed: rolling gaussian -> B-row -> row-DFT + Basym bookkeeping ----
    // Residual identity: R = B - Re(IFFT2(Tn)) = Basym + IDCT34(T - Tn), where
    // Basym = (B - B~)/2, B~ = index-negated B. Basym has 30 distinct values
    // (antisymmetric) -> replaces keeping B (64 regs) with 30 regs.
    float cpT[5][8], spT[3][8];
    float Ba0[3], Ba4[3];   // rows 0,4 self-pairs: (B[r][v] - B[r][8-v])/2, v=1..3
    float Ba[3][8];         // u=1..3 vs 8-u:      (B[u][v] - B[8-u][(8-v)%8])/2
    float Bs[3][8];         // saved B rows 1..3 awaiting partners 7..5
    {
        float h[3][8];
#pragma unroll
        for (int j = 0; j < 10; ++j) {
            float lft = __shfl_up(vb[j].w, 1);    // neighbor's col 7
            float rgt = __shfl_down(va[j].x, 1);  // neighbor's col 0
            if (lane == 0)  lft = va[j].y;        // reflect(-1) = col 1
            if (lane == 63) rgt = vb[j].z;        // reflect(512) = col 510
            float xr[10] = {lft, va[j].x, va[j].y, va[j].z, va[j].w,
                            vb[j].x, vb[j].y, vb[j].z, vb[j].w, rgt};
            float* hc = h[j % 3];
#pragma unroll
            for (int c = 0; c < 8; ++c)
                hc[c] = e * (xr[c] + xr[c + 2]) + xr[c + 1];
            if (j >= 2) {
                const float* h0 = h[(j - 2) % 3];
                const float* h1 = h[(j - 1) % 3];
                float Brow[8];
#pragma unroll
                for (int c = 0; c < 8; ++c)
                    Brow[c] = (e * (h0[c] + hc[c]) + h1[c]) * inv_s;
                const int m = j - 2;
                // row-DFT (transposed accumulation)
                float t[5], s[3];
                cos5(Brow, t);
                sin3(Brow, s);
#pragma unroll
                for (int v = 0; v < 5; ++v) cpT[v][m] = t[v];
#pragma unroll
                for (int v = 0; v < 3; ++v) spT[v][m] = s[v];
                // Basym bookkeeping (m is compile-time constant)
                if (m == 0) {
#pragma unroll
                    for (int v = 1; v <= 3; ++v) Ba0[v - 1] = (Brow[v] - Brow[8 - v]) * 0.5f;
                } else if (m == 4) {
#pragma unroll
                    for (int v = 1; v <= 3; ++v) Ba4[v - 1] = (Brow[v] - Brow[8 - v]) * 0.5f;
                } else if (m <= 3) {
#pragma unroll
                    for (int c = 0; c < 8; ++c) Bs[m - 1][c] = Brow[c];
                } else {  // m = 5,6,7 pairs u = 8-m = 3,2,1
                    const int u = 8 - m;
#pragma unroll
                    for (int v = 0; v < 8; ++v)
                        Ba[u - 1][v] = (Bs[u - 1][v] - Brow[(8 - v) & 7]) * 0.5f;
                }
            }
        }
    }

    // ---- forward column pass -> 34 distinct Tn values AND 34 distinct D = T - Tn ----
    float Tc0[5], Tc4[5], Dc0[5], Dc4[5];
    {
        float t[5];
        cos5(cpT[0], t);
#pragma unroll
        for (int i = 0; i < 5; ++i) { float tn = nlin(t[i]); Tc0[i] = tn; Dc0[i] = t[i] - tn; }
        cos5(cpT[4], t);
#pragma unroll
        for (int i = 0; i < 5; ++i) { float tn = nlin(t[i]); Tc4[i] = tn; Dc4[i] = t[i] - tn; }
    }
    float Tt[3], Tb[3], TA[3][3], TBm[3][3];
    float Dt[3], Db[3], DA[3][3], DBm[3][3];
#pragma unroll
    for (int vi = 0; vi < 3; ++vi) {
        float t[5], s[3];
        cos5(cpT[vi + 1], t);
        sin3(spT[vi], s);
        { float x = t[0]; float tn = nlin(x); Tt[vi] = tn; Dt[vi] = x - tn; }
        { float x = t[4]; float tn = nlin(x); Tb[vi] = tn; Db[vi] = x - tn; }
#pragma unroll
        for (int ui = 0; ui < 3; ++ui) {
            float xa = t[ui + 1] - s[ui];
            float na = nlin(xa);
            TA[vi][ui] = na; DA[vi][ui] = xa - na;
            float xb = t[ui + 1] + s[ui];
            float nb = nlin(xb);
            TBm[vi][ui] = nb; DBm[vi][ui] = xb - nb;
        }
    }

    const int chId = (p / 3) * 6 + (p % 3);
    float* __restrict__ oI = out + ((size_t)chId << 18);
    float* __restrict__ oR = out + ((size_t)(chId + 3) << 18);

    // ---- stream R first (Ba dies here): R = IDCT34(D) + Basym ----
    {
        float Rc0[5], Rc4[5], r0v[3], r4v[3], RAm[3][3], RBm[3][3];
        inverse34(Dc0, Dc4, Dt, Db, DA, DBm, Rc0, Rc4, r0v, r4v, RAm, RBm);
        float rec[8][8];
        expand34(Rc0, Rc4, r0v, r4v, RAm, RBm, rec);
        // add Basym (antisymmetric expansion)
#pragma unroll
        for (int v = 1; v <= 3; ++v) {
            rec[0][v] += Ba0[v - 1];
            rec[0][8 - v] -= Ba0[v - 1];
            rec[4][v] += Ba4[v - 1];
            rec[4][8 - v] -= Ba4[v - 1];
        }
#pragma unroll
        for (int u = 1; u <= 3; ++u)
#pragma unroll
            for (int v = 0; v < 8; ++v) {
                rec[u][v] += Ba[u - 1][v];
                rec[8 - u][(8 - v) & 7] -= Ba[u - 1][v];
            }
        haar_store(rec, oR, by, cx);
    }
    // ---- stream I: IDCT34(Tn) ----
    {
        float Rc0[5], Rc4[5], r0v[3], r4v[3], RAm[3][3], RBm[3][3];
        inverse34(Tc0, Tc4, Tt, Tb, TA, TBm, Rc0, Rc4, r0v, r4v, RAm, RBm);
        float rec[8][8];
        expand34(Rc0, Rc4, r0v, r4v, RAm, RBm, rec);
        haar_store(rec, oI, by, cx);
    }
}

extern "C" void kernel_launch(void* const* d_in, const int* in_sizes, int n_in,
                              void* d_out, int out_size, void* d_ws, size_t ws_size,
                              hipStream_t stream) {
    const float* I = (const float*)d_in[0];
    float* out = (float*)d_out;
    dim3 grid(16, 96);   // 16 workgroups x 4 waves = 64 block-rows per plane; 96 planes
    sas_fused<<<grid, dim3(256), 0, stream>>>(I, out);
}

// Round 6
// 301.889 us; speedup vs baseline: 1.1160x; 1.1160x over previous
//
#include <hip/hip_runtime.h>

#define HW 512
#define RA 0.35355339059327373f
#define RB 0.25f

__device__ __forceinline__ int reflect512(int v) {
    v = v < 0 ? -v : v;
    v = v > 511 ? 1022 - v : v;
    return v;
}

__device__ __forceinline__ float softt2(float x) {
    // soft-threshold at lambda=0.1 (operates on 2x-scaled Haar values)
    return copysignf(fmaxf(fabsf(x) - 0.1f, 0.0f), x);
}

__device__ __forceinline__ float nlin(float t) {
    float ca = fabsf(t);
    t = (ca < 2.5f) ? t * (ca * 0.4f) : t;
    return fminf(fmaxf(t, -10.0f), 10.0f);
}

// Haar refine, the two 0.5 scales folded into one 0.25 (exact: pow2 scaling
// commutes with rounding; 0.05f == 0.5f*0.1f exactly).
__device__ __forceinline__ void haar_quad(float a, float b, float c, float d,
                                          float& oa, float& ob, float& oc, float& od) {
    float s1 = a + b, s2 = c + d, d1 = a - b, d2 = c - d;
    float LL = s1 + s2, LH = s1 - s2, HL = d1 + d2, HH = d1 - d2;  // 2x scaled
    LH = softt2(LH); HL = softt2(HL); HH = softt2(HH);
    float u1 = LL + LH, u2 = HL + HH, w1 = LL - LH, w2 = HL - HH;
    oa = (u1 + u2) * 0.25f; ob = (u1 - u2) * 0.25f;
    oc = (w1 + w2) * 0.25f; od = (w1 - w2) * 0.25f;
}

// 8-pt cos-DFT, distinct outputs only (full: [t0,t1,t2,t3,t4,t3,t2,t1])
__device__ __forceinline__ void cos5(const float* __restrict__ x, float* __restrict__ t) {
    float e0 = x[0] + x[4], d0 = x[0] - x[4];
    float e1 = x[2] + x[6];
    float o0 = x[1] + x[5], m0 = x[1] - x[5];
    float o1 = x[3] + x[7], m1 = x[3] - x[7];
    float see = e0 + e1, dee = e0 - e1, soo = o0 + o1, dd = m0 - m1;
    t[0] = RA * (see + soo);
    t[4] = RA * (see - soo);
    t[2] = RA * dee;
    float a = RA * d0, b = RB * dd;
    t[1] = a + b;
    t[3] = a - b;
}

// 8-pt sin-DFT, distinct outputs only (full: [0,s0,s1,s2,0,-s2,-s1,-s0])
__device__ __forceinline__ void sin3(const float* __restrict__ x, float* __restrict__ s) {
    float d1 = x[2] - x[6];
    float m0 = x[1] - x[5];
    float o0 = x[1] + x[5];
    float o1 = x[3] + x[7], m1 = x[3] - x[7];
    float qq = m0 + m1;
    float a = RB * qq, b = RA * d1;
    s[0] = a + b;
    s[1] = RA * (o0 - o1);
    s[2] = a - b;
}

// cos-DFT of a symmetric 8-vector [x0,x1,x2,x3,x4,x3,x2,x1] (exact specialization)
__device__ __forceinline__ void cos5_sym(const float* __restrict__ x, float* __restrict__ t) {
    float e0 = x[0] + x[4], d0 = x[0] - x[4];
    float tx2 = 2.0f * x[2];
    float see = e0 + tx2, dee = e0 - tx2;
    float soo = 2.0f * (x[1] + x[3]);
    float m0 = x[1] - x[3];
    t[0] = RA * (see + soo);
    t[4] = RA * (see - soo);
    t[2] = RA * dee;
    float a = RA * d0, b = 0.5f * m0;   // RB * (2*m0)
    t[1] = a + b;
    t[3] = a - b;
}

// sin-DFT of an antisymmetric 8-vector [0,y0,y1,y2,0,-y2,-y1,-y0] (exact specialization)
__device__ __forceinline__ void sin3_asym(const float* __restrict__ y, float* __restrict__ s) {
    float a = 0.5f * (y[0] + y[2]);          // RB * (2*(y0+y2))
    float b = (2.0f * RA) * y[1];            // RA * (2*y1)
    s[0] = a + b;
    s[1] = (2.0f * RA) * (y[0] - y[2]);
    s[2] = a - b;
}

// Inverse 2D transform from the 34-value symmetric form to the 34-value
// centro-symmetric spatial form. Identical algebra to the verified round-0/3 path.
__device__ __forceinline__ void inverse34(
    const float c0[5], const float c4[5], const float tt[3], const float bb[3],
    const float A[3][3], const float Bm[3][3],
    float Rc0[5], float Rc4[5], float r0v[3], float r4v[3],
    float RAm[3][3], float RBm[3][3]) {
    // ---- inverse row pass: rows 0,4 symmetric; rows 5..7 mirror 3..1 ----
    float p2[5][5], q2[3][3];
    {
        float x0[5] = {c0[0], tt[0], tt[1], tt[2], c4[0]};
        cos5_sym(x0, p2[0]);
        float x4[5] = {c0[4], bb[0], bb[1], bb[2], c4[4]};
        cos5_sym(x4, p2[4]);
    }
#pragma unroll
    for (int u = 1; u <= 3; ++u) {
        float r8[8] = {c0[u], A[0][u - 1], A[1][u - 1], A[2][u - 1], c4[u],
                       Bm[2][u - 1], Bm[1][u - 1], Bm[0][u - 1]};
        cos5(r8, p2[u]);
        sin3(r8, q2[u - 1]);
    }
    // ---- inverse column pass: p2 cols symmetric, q2 cols antisymmetric ----
    {
        float cc0[5] = {p2[0][0], p2[1][0], p2[2][0], p2[3][0], p2[4][0]};
        cos5_sym(cc0, Rc0);
        float cc4[5] = {p2[0][4], p2[1][4], p2[2][4], p2[3][4], p2[4][4]};
        cos5_sym(cc4, Rc4);
    }
#pragma unroll
    for (int vi = 0; vi < 3; ++vi) {
        int v = vi + 1;
        float cs[5] = {p2[0][v], p2[1][v], p2[2][v], p2[3][v], p2[4][v]};
        float t[5];
        cos5_sym(cs, t);
        float y[3] = {q2[0][vi], q2[1][vi], q2[2][vi]};
        float s[3];
        sin3_asym(y, s);
        r0v[vi] = t[0];
        r4v[vi] = t[4];
#pragma unroll
        for (int ui = 0; ui < 3; ++ui) {
            RAm[vi][ui] = t[ui + 1] - s[ui];
            RBm[vi][ui] = t[ui + 1] + s[ui];
        }
    }
}

// Expand centro-symmetric 34-form to 8x8 (pure renames, SSA-aliased by regalloc).
__device__ __forceinline__ void expand34(
    const float Rc0[5], const float Rc4[5], const float r0v[3], const float r4v[3],
    const float RAm[3][3], const float RBm[3][3], float rec[8][8]) {
#pragma unroll
    for (int u = 0; u < 8; ++u) {
        int us = (u <= 4) ? u : 8 - u;
        rec[u][0] = Rc0[us];
        rec[u][4] = Rc4[us];
    }
#pragma unroll
    for (int v = 1; v < 8; ++v) {
        if (v == 4) continue;
        int vs = (v <= 4) ? v : 8 - v;
        bool vf = v > 4;
        rec[0][v] = r0v[vs - 1];
        rec[4][v] = r4v[vs - 1];
#pragma unroll
        for (int u = 1; u < 8; ++u) {
            if (u == 4) continue;
            int us = (u <= 4) ? u : 8 - u;
            bool uf = u > 4;
            rec[u][v] = (vf != uf) ? RBm[vs - 1][us - 1] : RAm[vs - 1][us - 1];
        }
    }
}

__device__ __forceinline__ void haar_store(const float rec[8][8],
                                           float* __restrict__ o, int by, int cx) {
#pragma unroll
    for (int qy = 0; qy < 4; ++qy) {
        float ti[2][8];
#pragma unroll
        for (int qx = 0; qx < 4; ++qx) {
            haar_quad(rec[2 * qy][2 * qx], rec[2 * qy][2 * qx + 1],
                      rec[2 * qy + 1][2 * qx], rec[2 * qy + 1][2 * qx + 1],
                      ti[0][2 * qx], ti[0][2 * qx + 1], ti[1][2 * qx], ti[1][2 * qx + 1]);
        }
        size_t base = (size_t)(by * 8 + 2 * qy) * HW + cx;
        *(float4*)&o[base]          = make_float4(ti[0][0], ti[0][1], ti[0][2], ti[0][3]);
        *(float4*)&o[base + 4]      = make_float4(ti[0][4], ti[0][5], ti[0][6], ti[0][7]);
        *(float4*)&o[base + HW]     = make_float4(ti[1][0], ti[1][1], ti[1][2], ti[1][3]);
        *(float4*)&o[base + HW + 4] = make_float4(ti[1][4], ti[1][5], ti[1][6], ti[1][7]);
    }
}

// (256,3): 168-VGPR budget. (256,4) forced a 128-cap on ~150-reg liveness ->
// allocator collapsed to 64 VGPR + ~500B/thread scratch (round 5: FETCH 155MB,
// WRITE 394MB vs ideal 100/201 -> 562MB moved, 143us). Spills cost more than
// the occupancy bought.
__launch_bounds__(256, 3)
__global__ void sas_fused(const float* __restrict__ in, float* __restrict__ out) {
    const int lane = threadIdx.x & 63;   // block-col 0..63
    const int wv = threadIdx.x >> 6;     // wave in workgroup
    const int p = blockIdx.y;            // plane (b*3+c)
    const int by = blockIdx.x * 4 + wv;  // block-row 0..63
    const float* __restrict__ inP = in + (size_t)p * (HW * HW);
    const int cx = lane * 8;

    const float e = 0.45783336f;                  // exp(-1/1.28)
    const float inv_s = 1.0f / ((1.0f + 2.0f * e) * (1.0f + 2.0f * e));

    // ---- issue ALL 10 row-loads upfront; sched_barrier pins them above consumption ----
    float4 va[10], vb[10];
#pragma unroll
    for (int j = 0; j < 10; ++j) {
        int gy = reflect512(by * 8 - 1 + j);
        const float* r = inP + (size_t)gy * HW + cx;
        va[j] = *(const float4*)r;
        vb[j] = *(const float4*)(r + 4);
    }
    __builtin_amdgcn_sched_barrier(0);   // keep all 20 loads in flight (MLP)

    // ---- streamed: rolling gaussian -> B-row -> row-DFT + Basym bookkeeping ----
    // Residual identity: R = B - Re(IFFT2(Tn)) = Basym + IDCT34(T - Tn), where
    // Basym = (B - B~)/2, B~ = index-negated B. Basym has 30 distinct values
    // (antisymmetric) -> replaces keeping B (64 regs) with 30 regs.
    float cpT[5][8], spT[3][8];
    float Ba0[3], Ba4[3];   // rows 0,4 self-pairs: (B[r][v] - B[r][8-v])/2, v=1..3
    float Ba[3][8];         // u=1..3 vs 8-u:      (B[u][v] - B[8-u][(8-v)%8])/2
    float Bs[3][8];         // saved B rows 1..3 awaiting partners 7..5
    {
        float h[3][8];
#pragma unroll
        for (int j = 0; j < 10; ++j) {
            float lft = __shfl_up(vb[j].w, 1);    // neighbor's col 7
            float rgt = __shfl_down(va[j].x, 1);  // neighbor's col 0
            if (lane == 0)  lft = va[j].y;        // reflect(-1) = col 1
            if (lane == 63) rgt = vb[j].z;        // reflect(512) = col 510
            float xr[10] = {lft, va[j].x, va[j].y, va[j].z, va[j].w,
                            vb[j].x, vb[j].y, vb[j].z, vb[j].w, rgt};
            float* hc = h[j % 3];
#pragma unroll
            for (int c = 0; c < 8; ++c)
                hc[c] = e * (xr[c] + xr[c + 2]) + xr[c + 1];
            if (j >= 2) {
                const float* h0 = h[(j - 2) % 3];
                const float* h1 = h[(j - 1) % 3];
                float Brow[8];
#pragma unroll
                for (int c = 0; c < 8; ++c)
                    Brow[c] = (e * (h0[c] + hc[c]) + h1[c]) * inv_s;
                const int m = j - 2;
                // row-DFT (transposed accumulation)
                float t[5], s[3];
                cos5(Brow, t);
                sin3(Brow, s);
#pragma unroll
                for (int v = 0; v < 5; ++v) cpT[v][m] = t[v];
#pragma unroll
                for (int v = 0; v < 3; ++v) spT[v][m] = s[v];
                // Basym bookkeeping (m is compile-time constant)
                if (m == 0) {
#pragma unroll
                    for (int v = 1; v <= 3; ++v) Ba0[v - 1] = (Brow[v] - Brow[8 - v]) * 0.5f;
                } else if (m == 4) {
#pragma unroll
                    for (int v = 1; v <= 3; ++v) Ba4[v - 1] = (Brow[v] - Brow[8 - v]) * 0.5f;
                } else if (m <= 3) {
#pragma unroll
                    for (int c = 0; c < 8; ++c) Bs[m - 1][c] = Brow[c];
                } else {  // m = 5,6,7 pairs u = 8-m = 3,2,1
                    const int u = 8 - m;
#pragma unroll
                    for (int v = 0; v < 8; ++v)
                        Ba[u - 1][v] = (Bs[u - 1][v] - Brow[(8 - v) & 7]) * 0.5f;
                }
            }
        }
    }

    // ---- forward column pass -> 34 distinct Tn values AND 34 distinct D = T - Tn ----
    float Tc0[5], Tc4[5], Dc0[5], Dc4[5];
    {
        float t[5];
        cos5(cpT[0], t);
#pragma unroll
        for (int i = 0; i < 5; ++i) { float tn = nlin(t[i]); Tc0[i] = tn; Dc0[i] = t[i] - tn; }
        cos5(cpT[4], t);
#pragma unroll
        for (int i = 0; i < 5; ++i) { float tn = nlin(t[i]); Tc4[i] = tn; Dc4[i] = t[i] - tn; }
    }
    float Tt[3], Tb[3], TA[3][3], TBm[3][3];
    float Dt[3], Db[3], DA[3][3], DBm[3][3];
#pragma unroll
    for (int vi = 0; vi < 3; ++vi) {
        float t[5], s[3];
        cos5(cpT[vi + 1], t);
        sin3(spT[vi], s);
        { float x = t[0]; float tn = nlin(x); Tt[vi] = tn; Dt[vi] = x - tn; }
        { float x = t[4]; float tn = nlin(x); Tb[vi] = tn; Db[vi] = x - tn; }
#pragma unroll
        for (int ui = 0; ui < 3; ++ui) {
            float xa = t[ui + 1] - s[ui];
            float na = nlin(xa);
            TA[vi][ui] = na; DA[vi][ui] = xa - na;
            float xb = t[ui + 1] + s[ui];
            float nb = nlin(xb);
            TBm[vi][ui] = nb; DBm[vi][ui] = xb - nb;
        }
    }

    const int chId = (p / 3) * 6 + (p % 3);
    float* __restrict__ oI = out + ((size_t)chId << 18);
    float* __restrict__ oR = out + ((size_t)(chId + 3) << 18);

    // ---- stream R first (Ba dies here): R = IDCT34(D) + Basym ----
    {
        float Rc0[5], Rc4[5], r0v[3], r4v[3], RAm[3][3], RBm[3][3];
        inverse34(Dc0, Dc4, Dt, Db, DA, DBm, Rc0, Rc4, r0v, r4v, RAm, RBm);
        float rec[8][8];
        expand34(Rc0, Rc4, r0v, r4v, RAm, RBm, rec);
        // add Basym (antisymmetric expansion)
#pragma unroll
        for (int v = 1; v <= 3; ++v) {
            rec[0][v] += Ba0[v - 1];
            rec[0][8 - v] -= Ba0[v - 1];
            rec[4][v] += Ba4[v - 1];
            rec[4][8 - v] -= Ba4[v - 1];
        }
#pragma unroll
        for (int u = 1; u <= 3; ++u)
#pragma unroll
            for (int v = 0; v < 8; ++v) {
                rec[u][v] += Ba[u - 1][v];
                rec[8 - u][(8 - v) & 7] -= Ba[u - 1][v];
            }
        haar_store(rec, oR, by, cx);
    }
    // ---- stream I: IDCT34(Tn) ----
    {
        float Rc0[5], Rc4[5], r0v[3], r4v[3], RAm[3][3], RBm[3][3];
        inverse34(Tc0, Tc4, Tt, Tb, TA, TBm, Rc0, Rc4, r0v, r4v, RAm, RBm);
        float rec[8][8];
        expand34(Rc0, Rc4, r0v, r4v, RAm, RBm, rec);
        haar_store(rec, oI, by, cx);
    }
}

extern "C" void kernel_launch(void* const* d_in, const int* in_sizes, int n_in,
                              void* d_out, int out_size, void* d_ws, size_t ws_size,
                              hipStream_t stream) {
    const float* I = (const float*)d_in[0];
    float* out = (float*)d_out;
    dim3 grid(16, 96);   // 16 workgroups x 4 waves = 64 block-rows per plane; 96 planes
    sas_fused<<<grid, dim3(256), 0, stream>>>(I, out);
}

// Round 7
// 291.967 us; speedup vs baseline: 1.1540x; 1.0340x over previous
//
#include <hip/hip_runtime.h>

#define HW 512
#define RA 0.35355339059327373f
#define RB 0.25f

__device__ __forceinline__ int reflect512(int v) {
    v = v < 0 ? -v : v;
    v = v > 511 ? 1022 - v : v;
    return v;
}

__device__ __forceinline__ float softt2(float x) {
    // soft-threshold at lambda=0.1 (operates on 2x-scaled Haar values)
    return copysignf(fmaxf(fabsf(x) - 0.1f, 0.0f), x);
}

__device__ __forceinline__ float nlin(float t) {
    float ca = fabsf(t);
    t = (ca < 2.5f) ? t * (ca * 0.4f) : t;
    return fminf(fmaxf(t, -10.0f), 10.0f);
}

// Haar refine, the two 0.5 scales folded into one 0.25 (exact: pow2 scaling
// commutes with rounding; 0.05f == 0.5f*0.1f exactly).
__device__ __forceinline__ void haar_quad(float a, float b, float c, float d,
                                          float& oa, float& ob, float& oc, float& od) {
    float s1 = a + b, s2 = c + d, d1 = a - b, d2 = c - d;
    float LL = s1 + s2, LH = s1 - s2, HL = d1 + d2, HH = d1 - d2;  // 2x scaled
    LH = softt2(LH); HL = softt2(HL); HH = softt2(HH);
    float u1 = LL + LH, u2 = HL + HH, w1 = LL - LH, w2 = HL - HH;
    oa = (u1 + u2) * 0.25f; ob = (u1 - u2) * 0.25f;
    oc = (w1 + w2) * 0.25f; od = (w1 - w2) * 0.25f;
}

// 8-pt cos-DFT, distinct outputs only (full: [t0,t1,t2,t3,t4,t3,t2,t1])
__device__ __forceinline__ void cos5(const float* __restrict__ x, float* __restrict__ t) {
    float e0 = x[0] + x[4], d0 = x[0] - x[4];
    float e1 = x[2] + x[6];
    float o0 = x[1] + x[5], m0 = x[1] - x[5];
    float o1 = x[3] + x[7], m1 = x[3] - x[7];
    float see = e0 + e1, dee = e0 - e1, soo = o0 + o1, dd = m0 - m1;
    t[0] = RA * (see + soo);
    t[4] = RA * (see - soo);
    t[2] = RA * dee;
    float a = RA * d0, b = RB * dd;
    t[1] = a + b;
    t[3] = a - b;
}

// 8-pt sin-DFT, distinct outputs only (full: [0,s0,s1,s2,0,-s2,-s1,-s0])
__device__ __forceinline__ void sin3(const float* __restrict__ x, float* __restrict__ s) {
    float d1 = x[2] - x[6];
    float m0 = x[1] - x[5];
    float o0 = x[1] + x[5];
    float o1 = x[3] + x[7], m1 = x[3] - x[7];
    float qq = m0 + m1;
    float a = RB * qq, b = RA * d1;
    s[0] = a + b;
    s[1] = RA * (o0 - o1);
    s[2] = a - b;
}

// cos-DFT of a symmetric 8-vector [x0,x1,x2,x3,x4,x3,x2,x1] (exact specialization)
__device__ __forceinline__ void cos5_sym(const float* __restrict__ x, float* __restrict__ t) {
    float e0 = x[0] + x[4], d0 = x[0] - x[4];
    float tx2 = 2.0f * x[2];
    float see = e0 + tx2, dee = e0 - tx2;
    float soo = 2.0f * (x[1] + x[3]);
    float m0 = x[1] - x[3];
    t[0] = RA * (see + soo);
    t[4] = RA * (see - soo);
    t[2] = RA * dee;
    float a = RA * d0, b = 0.5f * m0;   // RB * (2*m0)
    t[1] = a + b;
    t[3] = a - b;
}

// sin-DFT of an antisymmetric 8-vector [0,y0,y1,y2,0,-y2,-y1,-y0] (exact specialization)
__device__ __forceinline__ void sin3_asym(const float* __restrict__ y, float* __restrict__ s) {
    float a = 0.5f * (y[0] + y[2]);          // RB * (2*(y0+y2))
    float b = (2.0f * RA) * y[1];            // RA * (2*y1)
    s[0] = a + b;
    s[1] = (2.0f * RA) * (y[0] - y[2]);
    s[2] = a - b;
}

// Inverse 2D transform from the 34-value symmetric form to the 34-value
// centro-symmetric spatial form. Identical algebra to the verified round-0/3 path.
__device__ __forceinline__ void inverse34(
    const float c0[5], const float c4[5], const float tt[3], const float bb[3],
    const float A[3][3], const float Bm[3][3],
    float Rc0[5], float Rc4[5], float r0v[3], float r4v[3],
    float RAm[3][3], float RBm[3][3]) {
    // ---- inverse row pass: rows 0,4 symmetric; rows 5..7 mirror 3..1 ----
    float p2[5][5], q2[3][3];
    {
        float x0[5] = {c0[0], tt[0], tt[1], tt[2], c4[0]};
        cos5_sym(x0, p2[0]);
        float x4[5] = {c0[4], bb[0], bb[1], bb[2], c4[4]};
        cos5_sym(x4, p2[4]);
    }
#pragma unroll
    for (int u = 1; u <= 3; ++u) {
        float r8[8] = {c0[u], A[0][u - 1], A[1][u - 1], A[2][u - 1], c4[u],
                       Bm[2][u - 1], Bm[1][u - 1], Bm[0][u - 1]};
        cos5(r8, p2[u]);
        sin3(r8, q2[u - 1]);
    }
    // ---- inverse column pass: p2 cols symmetric, q2 cols antisymmetric ----
    {
        float cc0[5] = {p2[0][0], p2[1][0], p2[2][0], p2[3][0], p2[4][0]};
        cos5_sym(cc0, Rc0);
        float cc4[5] = {p2[0][4], p2[1][4], p2[2][4], p2[3][4], p2[4][4]};
        cos5_sym(cc4, Rc4);
    }
#pragma unroll
    for (int vi = 0; vi < 3; ++vi) {
        int v = vi + 1;
        float cs[5] = {p2[0][v], p2[1][v], p2[2][v], p2[3][v], p2[4][v]};
        float t[5];
        cos5_sym(cs, t);
        float y[3] = {q2[0][vi], q2[1][vi], q2[2][vi]};
        float s[3];
        sin3_asym(y, s);
        r0v[vi] = t[0];
        r4v[vi] = t[4];
#pragma unroll
        for (int ui = 0; ui < 3; ++ui) {
            RAm[vi][ui] = t[ui + 1] - s[ui];
            RBm[vi][ui] = t[ui + 1] + s[ui];
        }
    }
}

// Expand centro-symmetric 34-form to 8x8 (pure renames, SSA-aliased by regalloc).
__device__ __forceinline__ void expand34(
    const float Rc0[5], const float Rc4[5], const float r0v[3], const float r4v[3],
    const float RAm[3][3], const float RBm[3][3], float rec[8][8]) {
#pragma unroll
    for (int u = 0; u < 8; ++u) {
        int us = (u <= 4) ? u : 8 - u;
        rec[u][0] = Rc0[us];
        rec[u][4] = Rc4[us];
    }
#pragma unroll
    for (int v = 1; v < 8; ++v) {
        if (v == 4) continue;
        int vs = (v <= 4) ? v : 8 - v;
        bool vf = v > 4;
        rec[0][v] = r0v[vs - 1];
        rec[4][v] = r4v[vs - 1];
#pragma unroll
        for (int u = 1; u < 8; ++u) {
            if (u == 4) continue;
            int us = (u <= 4) ? u : 8 - u;
            bool uf = u > 4;
            rec[u][v] = (vf != uf) ? RBm[vs - 1][us - 1] : RAm[vs - 1][us - 1];
        }
    }
}

__device__ __forceinline__ void haar_store(const float rec[8][8],
                                           float* __restrict__ o, int by, int cx) {
#pragma unroll
    for (int qy = 0; qy < 4; ++qy) {
        float ti[2][8];
#pragma unroll
        for (int qx = 0; qx < 4; ++qx) {
            haar_quad(rec[2 * qy][2 * qx], rec[2 * qy][2 * qx + 1],
                      rec[2 * qy + 1][2 * qx], rec[2 * qy + 1][2 * qx + 1],
                      ti[0][2 * qx], ti[0][2 * qx + 1], ti[1][2 * qx], ti[1][2 * qx + 1]);
        }
        size_t base = (size_t)(by * 8 + 2 * qy) * HW + cx;
        *(float4*)&o[base]          = make_float4(ti[0][0], ti[0][1], ti[0][2], ti[0][3]);
        *(float4*)&o[base + 4]      = make_float4(ti[0][4], ti[0][5], ti[0][6], ti[0][7]);
        *(float4*)&o[base + HW]     = make_float4(ti[1][0], ti[1][1], ti[1][2], ti[1][3]);
        *(float4*)&o[base + HW + 4] = make_float4(ti[1][4], ti[1][5], ti[1][6], ti[1][7]);
    }
}

// Horizontal gaussian of row J into named array H (all indices literal).
#define HPASS(J, H) {                                                          \
    float lft = __shfl_up(vb[J].w, 1);                                         \
    float rgt = __shfl_down(va[J].x, 1);                                       \
    if (lane == 0)  lft = va[J].y;                                             \
    if (lane == 63) rgt = vb[J].z;                                             \
    float xr[10] = {lft, va[J].x, va[J].y, va[J].z, va[J].w,                   \
                    vb[J].x, vb[J].y, vb[J].z, vb[J].w, rgt};                  \
    _Pragma("unroll")                                                          \
    for (int c = 0; c < 8; ++c) H[c] = e * (xr[c] + xr[c + 2]) + xr[c + 1];    \
}

// Vertical gaussian from named rows H0,H1,H2 -> B-row M; row-DFT into cpT/spT;
// Basym bookkeeping. M is a LITERAL -> every branch/index constant-folds.
// (No pointer variables anywhere: round-2/6 showed `float* hc = h[j%3]` defeats
// SROA -> arrays land in scratch: 84 VGPR + ~95MB scratch traffic, 140us.)
#define BROWC(M, H0, H1, H2) {                                                 \
    float Brow[8];                                                             \
    _Pragma("unroll")                                                          \
    for (int c = 0; c < 8; ++c)                                                \
        Brow[c] = (e * (H0[c] + H2[c]) + H1[c]) * inv_s;                       \
    float t5[5], s3[3];                                                        \
    cos5(Brow, t5);                                                            \
    sin3(Brow, s3);                                                            \
    _Pragma("unroll")                                                          \
    for (int v = 0; v < 5; ++v) cpT[v][M] = t5[v];                             \
    _Pragma("unroll")                                                          \
    for (int v = 0; v < 3; ++v) spT[v][M] = s3[v];                             \
    if (M == 0) {                                                              \
        _Pragma("unroll")                                                      \
        for (int v = 1; v <= 3; ++v) Ba0[v - 1] = (Brow[v] - Brow[8 - v]) * 0.5f; \
    } else if (M == 4) {                                                       \
        _Pragma("unroll")                                                      \
        for (int v = 1; v <= 3; ++v) Ba4[v - 1] = (Brow[v] - Brow[8 - v]) * 0.5f; \
    } else if (M <= 3) {                                                       \
        _Pragma("unroll")                                                      \
        for (int c = 0; c < 8; ++c) Bs[(M) > 0 ? (M) - 1 : 0][c] = Brow[c];    \
    } else {                                                                   \
        _Pragma("unroll")                                                      \
        for (int v = 0; v < 8; ++v)                                            \
            Ba[(M) > 4 ? 7 - (M) : 0][v] =                                     \
                (Bs[(M) > 4 ? 7 - (M) : 0][v] - Brow[(8 - v) & 7]) * 0.5f;     \
    }                                                                          \
}

// (256,3): 168-VGPR budget. (256,4) forced a 128-cap on ~150-reg liveness ->
// spill collapse (round 5: 562MB moved, 143us).
__launch_bounds__(256, 3)
__global__ void sas_fused(const float* __restrict__ in, float* __restrict__ out) {
    const int lane = threadIdx.x & 63;   // block-col 0..63
    const int wv = threadIdx.x >> 6;     // wave in workgroup
    const int p = blockIdx.y;            // plane (b*3+c)
    const int by = blockIdx.x * 4 + wv;  // block-row 0..63
    const float* __restrict__ inP = in + (size_t)p * (HW * HW);
    const int cx = lane * 8;

    const float e = 0.45783336f;                  // exp(-1/1.28)
    const float inv_s = 1.0f / ((1.0f + 2.0f * e) * (1.0f + 2.0f * e));

    // ---- issue ALL 10 row-loads upfront; sched_barrier pins them above consumption ----
    float4 va[10], vb[10];
#pragma unroll
    for (int j = 0; j < 10; ++j) {
        int gy = reflect512(by * 8 - 1 + j);
        const float* r = inP + (size_t)gy * HW + cx;
        va[j] = *(const float4*)r;
        vb[j] = *(const float4*)(r + 4);
    }
    __builtin_amdgcn_sched_barrier(0);   // keep all 20 loads in flight (MLP)

    // ---- streamed: gaussian -> B-row -> row-DFT + Basym, all static names ----
    // Residual identity: R = B - Re(IFFT2(Tn)) = Basym + IDCT34(T - Tn), where
    // Basym = (B - B~)/2 (antisymmetric, 30 distinct values).
    float cpT[5][8], spT[3][8];
    float Ba0[3], Ba4[3];   // rows 0,4 self-pairs: (B[r][v] - B[r][8-v])/2, v=1..3
    float Ba[3][8];         // u=1..3 vs 8-u:      (B[u][v] - B[8-u][(8-v)%8])/2
    float Bs[3][8];         // saved B rows 1..3 awaiting partners 7..5
    {
        float hA[8], hB[8], hC[8];
        HPASS(0, hA);
        HPASS(1, hB);
        HPASS(2, hC); BROWC(0, hA, hB, hC);
        HPASS(3, hA); BROWC(1, hB, hC, hA);
        HPASS(4, hB); BROWC(2, hC, hA, hB);
        HPASS(5, hC); BROWC(3, hA, hB, hC);
        HPASS(6, hA); BROWC(4, hB, hC, hA);
        HPASS(7, hB); BROWC(5, hC, hA, hB);
        HPASS(8, hC); BROWC(6, hA, hB, hC);
        HPASS(9, hA); BROWC(7, hB, hC, hA);
    }

    // ---- forward column pass -> 34 distinct Tn values AND 34 distinct D = T - Tn ----
    float Tc0[5], Tc4[5], Dc0[5], Dc4[5];
    {
        float t[5];
        cos5(cpT[0], t);
#pragma unroll
        for (int i = 0; i < 5; ++i) { float tn = nlin(t[i]); Tc0[i] = tn; Dc0[i] = t[i] - tn; }
        cos5(cpT[4], t);
#pragma unroll
        for (int i = 0; i < 5; ++i) { float tn = nlin(t[i]); Tc4[i] = tn; Dc4[i] = t[i] - tn; }
    }
    float Tt[3], Tb[3], TA[3][3], TBm[3][3];
    float Dt[3], Db[3], DA[3][3], DBm[3][3];
#pragma unroll
    for (int vi = 0; vi < 3; ++vi) {
        float t[5], s[3];
        cos5(cpT[vi + 1], t);
        sin3(spT[vi], s);
        { float x = t[0]; float tn = nlin(x); Tt[vi] = tn; Dt[vi] = x - tn; }
        { float x = t[4]; float tn = nlin(x); Tb[vi] = tn; Db[vi] = x - tn; }
#pragma unroll
        for (int ui = 0; ui < 3; ++ui) {
            float xa = t[ui + 1] - s[ui];
            float na = nlin(xa);
            TA[vi][ui] = na; DA[vi][ui] = xa - na;
            float xb = t[ui + 1] + s[ui];
            float nb = nlin(xb);
            TBm[vi][ui] = nb; DBm[vi][ui] = xb - nb;
        }
    }

    const int chId = (p / 3) * 6 + (p % 3);
    float* __restrict__ oI = out + ((size_t)chId << 18);
    float* __restrict__ oR = out + ((size_t)(chId + 3) << 18);

    // ---- stream R first (Ba dies here): R = IDCT34(D) + Basym ----
    {
        float Rc0[5], Rc4[5], r0v[3], r4v[3], RAm[3][3], RBm[3][3];
        inverse34(Dc0, Dc4, Dt, Db, DA, DBm, Rc0, Rc4, r0v, r4v, RAm, RBm);
        float rec[8][8];
        expand34(Rc0, Rc4, r0v, r4v, RAm, RBm, rec);
        // add Basym (antisymmetric expansion)
#pragma unroll
        for (int v = 1; v <= 3; ++v) {
            rec[0][v] += Ba0[v - 1];
            rec[0][8 - v] -= Ba0[v - 1];
            rec[4][v] += Ba4[v - 1];
            rec[4][8 - v] -= Ba4[v - 1];
        }
#pragma unroll
        for (int u = 1; u <= 3; ++u)
#pragma unroll
            for (int v = 0; v < 8; ++v) {
                rec[u][v] += Ba[u - 1][v];
                rec[8 - u][(8 - v) & 7] -= Ba[u - 1][v];
            }
        haar_store(rec, oR, by, cx);
    }
    // ---- stream I: IDCT34(Tn) ----
    {
        float Rc0[5], Rc4[5], r0v[3], r4v[3], RAm[3][3], RBm[3][3];
        inverse34(Tc0, Tc4, Tt, Tb, TA, TBm, Rc0, Rc4, r0v, r4v, RAm, RBm);
        float rec[8][8];
        expand34(Rc0, Rc4, r0v, r4v, RAm, RBm, rec);
        haar_store(rec, oI, by, cx);
    }
}

extern "C" void kernel_launch(void* const* d_in, const int* in_sizes, int n_in,
                              void* d_out, int out_size, void* d_ws, size_t ws_size,
                              hipStream_t stream) {
    const float* I = (const float*)d_in[0];
    float* out = (float*)d_out;
    dim3 grid(16, 96);   // 16 workgroups x 4 waves = 64 block-rows per plane; 96 planes
    sas_fused<<<grid, dim3(256), 0, stream>>>(I, out);
}